// Round 1
// baseline (166.868 us; speedup 1.0000x reference)
//
#include <hip/hip_runtime.h>
#include <hip/hip_bf16.h>

// RoI bilinear pooling.
// img : (1, H=200, W=200, C=256) fp32, NHWC  -> channel vectors contiguous (1 KiB)
// rois: (1, N=2000, 4) fp32 (integer-valued x,y,w,h)
// out : (1, N, ps, ps, C) fp32
//
// One wave (64 lanes) per (roi,py,px) cell; lane handles one float4 of the
// 256-channel vector. 4 cells per 256-thread block. All loads/stores are
// 16 B/lane coalesced.

__global__ __launch_bounds__(256) void RoIPool_53575422050620_kernel(
    const float* __restrict__ feat,   // H*W*C
    const float* __restrict__ rois,   // N*4
    const int*   __restrict__ psp,    // pool_size scalar
    float*       __restrict__ out,    // n_cells*C
    int n_cells, int H, int W, int C)
{
    const int ps   = psp[0];
    const int cell = blockIdx.x * 4 + (threadIdx.x >> 6);
    if (cell >= n_cells) return;
    const int lane = threadIdx.x & 63;

    const int pp  = ps * ps;
    const int roi = cell / pp;
    const int rem = cell - roi * pp;
    const int py  = rem / ps;
    const int px  = rem - py * ps;

    // rois row: 16 B aligned (stride 4 floats)
    const float4 r = reinterpret_cast<const float4*>(rois)[roi];
    const int x = (int)r.x;   // astype(int32) == trunc; values are >= 0
    const int y = (int)r.y;
    const int w = (int)r.z;
    const int h = (int)r.w;

    // match reference fp32 math exactly
    const float sy    = (float)h / (float)ps;
    const float sx    = (float)w / (float)ps;
    const float src_y = (float)py * sy;
    const float src_x = (float)px * sx;
    const int y0 = (int)floorf(src_y);
    const int x0 = (int)floorf(src_x);
    const float wy = src_y - (float)y0;
    const float wx = src_x - (float)x0;

    const int gy0 = min(max(y + min(max(y0,     0), h - 1), 0), H - 1);
    const int gy1 = min(max(y + min(max(y0 + 1, 0), h - 1), 0), H - 1);
    const int gx0 = min(max(x + min(max(x0,     0), w - 1), 0), W - 1);
    const int gx1 = min(max(x + min(max(x0 + 1, 0), w - 1), 0), W - 1);

    const int C4 = C >> 2;
    const float4* __restrict__ f4 = reinterpret_cast<const float4*>(feat);
    float4* __restrict__ o4 = reinterpret_cast<float4*>(out);

    const size_t b00 = (size_t)(gy0 * W + gx0) * C4;
    const size_t b01 = (size_t)(gy0 * W + gx1) * C4;
    const size_t b10 = (size_t)(gy1 * W + gx0) * C4;
    const size_t b11 = (size_t)(gy1 * W + gx1) * C4;
    const size_t ob  = (size_t)cell * C4;

    const float omwx = 1.0f - wx;
    const float omwy = 1.0f - wy;

    for (int cv = lane; cv < C4; cv += 64) {
        const float4 v00 = f4[b00 + cv];
        const float4 v01 = f4[b01 + cv];
        const float4 v10 = f4[b10 + cv];
        const float4 v11 = f4[b11 + cv];
        float4 o;
        o.x = (v00.x * omwx + v01.x * wx) * omwy + (v10.x * omwx + v11.x * wx) * wy;
        o.y = (v00.y * omwx + v01.y * wx) * omwy + (v10.y * omwx + v11.y * wx) * wy;
        o.z = (v00.z * omwx + v01.z * wx) * omwy + (v10.z * omwx + v11.z * wx) * wy;
        o.w = (v00.w * omwx + v01.w * wx) * omwy + (v10.w * omwx + v11.w * wx) * wy;
        o4[ob + cv] = o;
    }
}

extern "C" void kernel_launch(void* const* d_in, const int* in_sizes, int n_in,
                              void* d_out, int out_size, void* d_ws, size_t ws_size,
                              hipStream_t stream) {
    const float* img  = (const float*)d_in[0];
    const float* rois = (const float*)d_in[1];
    const int*   psp  = (const int*)d_in[2];
    float*       out  = (float*)d_out;

    const int H = 200, W = 200, C = 256;
    const int n_cells = out_size / C;           // N * ps * ps
    const int blocks  = (n_cells + 3) / 4;      // 4 cells (waves) per block

    RoIPool_53575422050620_kernel<<<blocks, 256, 0, stream>>>(
        img, rois, psp, out, n_cells, H, W, C);
}